// Round 9
// baseline (160.141 us; speedup 1.0000x reference)
//
#include <hip/hip_runtime.h>
#include <stdint.h>

typedef __bf16 bf16x8 __attribute__((ext_vector_type(8)));
typedef float floatx4 __attribute__((ext_vector_type(4)));
typedef unsigned int u32x4 __attribute__((ext_vector_type(4)));
typedef unsigned short u16;
typedef unsigned int u32;

#define CIN   64
#define COUT  128
#define H_    1855
#define KNB   6
#define KTOT  448      // (1+KNB)*CIN
#define NSTEPS 14      // KTOT / 32
#define NT8   232      // ceil(1855/8) 8-h tiles

// ws layout (bytes)
#define WP_OFF   ((size_t)H_ * 4096 * 2)
#define CINV_OFF (WP_OFF + (size_t)COUT * KTOT * 2)
#define ZERO_OFF (CINV_OFF + 7424)            // 128-B zero page, 256-B aligned

#define PIN4(v) asm volatile("" : "+v"(v))

static __device__ inline u16 f32_to_bf16(float f) {
    u32 u = __float_as_uint(f);
    u32 r = (u + 0x7FFFu + ((u >> 16) & 1u)) >> 16;
    return (u16)r;
}

// ---- K1: transpose x f32 [bc][h] -> xt3 bf16 [h][bc] ---------------------
__global__ __launch_bounds__(256) void k_transpose(const float* __restrict__ x,
                                                   u16* __restrict__ xt3) {
    __shared__ u16 tile[64][65];
    int h0  = blockIdx.x * 64;
    int bc0 = blockIdx.y * 64;
    int lane = threadIdx.x & 63;
    int rowq = threadIdx.x >> 6;
    int h = h0 + lane;
    bool hv = h < H_;
#pragma unroll
    for (int i = 0; i < 16; ++i) {
        int row = i * 4 + rowq;
        u16 v = 0;
        if (hv) v = f32_to_bf16(x[(size_t)(bc0 + row) * H_ + h]);
        tile[row][lane] = v;
    }
    __syncthreads();
#pragma unroll
    for (int i = 0; i < 16; ++i) {
        int hr = i * 4 + rowq;
        int hh = h0 + hr;
        if (hh < H_) xt3[(size_t)hh * 4096 + bc0 + lane] = tile[lane][hr];
    }
}

// ---- K2: pack weights + inverse counts + 128-B zero page -----------------
__global__ __launch_bounds__(256) void k_pack(const float* __restrict__ wc,
                                              const float* __restrict__ wn,
                                              const int* __restrict__ nbr,
                                              u16* __restrict__ wp,
                                              float* __restrict__ cInvG,
                                              u32* __restrict__ zeroPg) {
    int tg = blockIdx.x * 256 + threadIdx.x;
    if (tg < 32) zeroPg[tg] = 0u;            // 128-B zero page
    if (tg < H_) {
        int cnt = 1;
#pragma unroll
        for (int j = 0; j < KNB; ++j) cnt += (nbr[tg * KNB + j] >= 0) ? 1 : 0;
        cInvG[tg] = 1.0f / (float)cnt;
    }
    if (tg >= COUT * KTOT) return;
    int o = tg / KTOT;
    int rem = tg - o * KTOT;
    int s = rem >> 6, c = rem & 63;
    float v = (s == 0) ? wc[o * CIN + c]
                       : wn[(o * CIN + c) * KNB + (s - 1)];
    wp[tg] = f32_to_bf16(v);
}

// ---- K3: barrier-free, LDS-free gather-GEMM ------------------------------
// 512 blocks x 4 waves = 2048 fully-independent waves (no __syncthreads).
// Wave task: one 8-h tile for one (b-pair, m-quarter): M=32 o (A=W pinned in
// regs), N=16 = 2b x 8h, K=448 = 14 kk-steps. B-fragments are loaded
// DIRECTLY from xt3 global in MFMA layout: lane(col=n: b_l=col>>3,h_l=col&7;
// quad=k-chunk) -> per kk one independent b128 load, s=kk>>1.
// XCD pin: g&7 = bp&7 -> each XCD gathers only its 1.9-MB xt3 column slice.
__global__ __launch_bounds__(256, 2) void k_main(const u16* __restrict__ xt3,
                                                 const u16* __restrict__ wp,
                                                 const int* __restrict__ nbr,
                                                 const float* __restrict__ bias,
                                                 const float* __restrict__ cInvG,
                                                 const u16* __restrict__ zeroPg,
                                                 float* __restrict__ out) {
    int tid  = threadIdx.x;
    int g    = blockIdx.x;        // 0..511
    int wv   = tid >> 6;
    int lane = tid & 63;
    int col  = lane & 15;
    int quad = lane >> 4;

    int bpLo = g & 7;             // XCD id
    int bpHi = (g >> 3) & 3;
    int mq   = (g >> 5) & 3;      // m-quarter
    int hq   = g >> 7;            // 0..3
    int bp   = bpHi * 8 + bpLo;   // b-pair 0..31
    int b0   = bp * 2;
    int m0   = mq * 32;

    int b_l  = col >> 3;          // 0..1
    int h_l  = col & 7;           // 0..7
    size_t bcol = (size_t)(b0 + b_l) * 64;   // u16 offset within an xt3 row

    // A fragments for this wave's 32 o-rows: A[m=col][k=quad*8+j]
    u32x4 afrag[2][NSTEPS];
#pragma unroll
    for (int mt = 0; mt < 2; ++mt) {
        int o = m0 + mt * 16 + col;
#pragma unroll
        for (int kk = 0; kk < NSTEPS; ++kk)
            afrag[mt][kk] = *(const u32x4*)(wp + o * KTOT + kk * 32 + quad * 8);
    }
#pragma unroll
    for (int mt = 0; mt < 2; ++mt)
#pragma unroll
        for (int kk = 0; kk < NSTEPS; ++kk)
            PIN4(afrag[mt][kk]);

    float biasv[2][4];
#pragma unroll
    for (int mt = 0; mt < 2; ++mt)
#pragma unroll
        for (int r = 0; r < 4; ++r)
            biasv[mt][r] = bias[m0 + mt * 16 + quad * 4 + r];

    // Task loop: 8-h tiles strided by 16 across the block's 4 waves.
    for (int t = hq * 4 + wv; t < NT8; t += 16) {
        int h  = t * 8 + h_l;
        int hcl = h < H_ ? h : 0;            // clamped (reads valid, store masked)
        bool hv = h < H_;

        // 7 per-lane gather base pointers (center + 6 neighbors)
        const u16* base[7];
        base[0] = xt3 + (size_t)hcl * 4096 + bcol;
#pragma unroll
        for (int s = 1; s < 7; ++s) {
            int nv = nbr[hcl * KNB + (s - 1)];
            base[s] = (nv >= 0) ? (xt3 + (size_t)nv * 4096 + bcol) : zeroPg;
        }

        floatx4 acc0 = (floatx4){0.f, 0.f, 0.f, 0.f};
        floatx4 acc1 = (floatx4){0.f, 0.f, 0.f, 0.f};

#pragma unroll
        for (int kk = 0; kk < NSTEPS; ++kk) {
            // k = kk*32 + quad*8 + j ; s = k>>6 ; c = k&63
            bf16x8 bf = *(const bf16x8*)(base[kk >> 1] + (kk & 1) * 32 + quad * 8);
            acc0 = __builtin_amdgcn_mfma_f32_16x16x32_bf16(
                __builtin_bit_cast(bf16x8, afrag[0][kk]), bf, acc0, 0, 0, 0);
            acc1 = __builtin_amdgcn_mfma_f32_16x16x32_bf16(
                __builtin_bit_cast(bf16x8, afrag[1][kk]), bf, acc1, 0, 0, 0);
        }

        // epilogue: C/D col=lane&15 -> n (b_l,h), row=quad*4+r -> o
        float ic = cInvG[hcl];
        size_t obase = ((size_t)(b0 + b_l) * COUT) * H_ + h;
#pragma unroll
        for (int r = 0; r < 4; ++r) {
            int o0 = m0 + quad * 4 + r;
            if (hv) {
                out[obase + (size_t)o0 * H_]        = acc0[r] * ic + biasv[0][r];
                out[obase + (size_t)(o0 + 16) * H_] = acc1[r] * ic + biasv[1][r];
            }
        }
    }
}

extern "C" void kernel_launch(void* const* d_in, const int* in_sizes, int n_in,
                              void* d_out, int out_size, void* d_ws, size_t ws_size,
                              hipStream_t stream) {
    const float* x    = (const float*)d_in[0];   // f32 [64,64,1855]
    const int*   nbr  = (const int*)d_in[1];     // int32 [1855,6]
    const float* wc   = (const float*)d_in[2];   // f32 [128,64]
    const float* wn   = (const float*)d_in[3];   // f32 [128,64,6]
    const float* bias = (const float*)d_in[4];   // f32 [128]

    u16*   xt3    = (u16*)d_ws;
    u16*   wp     = (u16*)((char*)d_ws + WP_OFF);
    float* cInvG  = (float*)((char*)d_ws + CINV_OFF);
    u32*   zeroPg = (u32*)((char*)d_ws + ZERO_OFF);

    k_pack<<<dim3((COUT * KTOT + 255) / 256), dim3(256), 0, stream>>>(
        wc, wn, nbr, wp, cInvG, zeroPg);
    k_transpose<<<dim3(29, 64), dim3(256), 0, stream>>>(x, xt3);
    k_main<<<dim3(512), dim3(256), 0, stream>>>(
        xt3, wp, nbr, bias, cInvG, (const u16*)zeroPg, (float*)d_out);
}